// Round 4
// baseline (410.067 us; speedup 1.0000x reference)
//
#include <hip/hip_runtime.h>

typedef float f32x2 __attribute__((ext_vector_type(2)));
typedef float f32x4 __attribute__((ext_vector_type(4)));

#define NB 512
#define DD 32
#define HH 128
#define NTP 64
#define NINNER 8

// packed dual-FP32 FMA: acc.lo += a.lo*b.lo ; acc.hi += a.hi*b.hi
__device__ __forceinline__ void pk_fma2(f32x2& acc, f32x2 a, f32x2 b) {
    asm("v_pk_fma_f32 %0, %1, %2, %0" : "+v"(acc) : "v"(a), "v"(b));
}
// hardware transcendentals (avoid glibc math.h macro collisions)
__device__ __forceinline__ float fexp2(float x) { float r; asm("v_exp_f32 %0, %1" : "=v"(r) : "v"(x)); return r; }
__device__ __forceinline__ float flog2(float x) { float r; asm("v_log_f32 %0, %1" : "=v"(r) : "v"(x)); return r; }
__device__ __forceinline__ float frcpa(float x) { float r; asm("v_rcp_f32 %0, %1" : "=v"(r) : "v"(x)); return r; }

// x + value_from_lane(l^32) via VALU permlane (vs ds_bpermute ~50cyc)
__device__ __forceinline__ float xadd32(float x) {
#if __has_builtin(__builtin_amdgcn_permlane32_swap)
    auto r = __builtin_amdgcn_permlane32_swap(__float_as_int(x), __float_as_int(x), false, false);
    return __int_as_float(r[0]) + __int_as_float(r[1]);
#else
    return x + __shfl_xor(x, 32, 64);
#endif
}

#define DPP_ADD(s, ctrl) \
    s += __int_as_float(__builtin_amdgcn_update_dpp(0, __float_as_int(s), ctrl, 0xf, 0xf, true))

// 64-lane sum, returned wave-uniform (classic gfx9 DPP ladder, ~VALU speed)
__device__ __forceinline__ float wave_sum(float s) {
#if __has_builtin(__builtin_amdgcn_update_dpp) && __has_builtin(__builtin_amdgcn_readlane)
    DPP_ADD(s, 0x111);  // row_shr:1
    DPP_ADD(s, 0x112);  // row_shr:2
    DPP_ADD(s, 0x114);  // row_shr:4
    DPP_ADD(s, 0x118);  // row_shr:8
    DPP_ADD(s, 0x142);  // row_bcast:15
    DPP_ADD(s, 0x143);  // row_bcast:31
    return __int_as_float(__builtin_amdgcn_readlane(__float_as_int(s), 63));
#else
#pragma unroll
    for (int m = 1; m <= 32; m <<= 1) s += __shfl_xor(s, m, 64);
    return s;
#endif
}

__global__ __launch_bounds__(64, 1)
void ude_kernel(const float* __restrict__ gy0, const float* __restrict__ gts,
                const float* __restrict__ gW1, const float* __restrict__ gb1,
                const float* __restrict__ gW2, const float* __restrict__ gb2,
                float* __restrict__ gout)
{
    constexpr float A21 = 0.161f;
    constexpr float A31 = -0.008480655492356989f, A32 = 0.335480655492357f;
    constexpr float A41 = 2.8971530571054935f, A42 = -6.359448489975075f, A43 = 4.3622954328695815f;
    constexpr float A51 = 5.325864828439257f, A52 = -11.748883564062828f, A53 = 7.4955393428898365f, A54 = -0.09249506636175525f;
    constexpr float A61 = 5.86145544294642f, A62 = -12.92096931784711f, A63 = 8.159367898576159f, A64 = -0.071584973281401f, A65 = -0.028269050394068383f;
    constexpr float B1c = 0.09646076681806523f, B2c = 0.01f, B3c = 0.4798896504144996f,
                    B4c = 1.379008574103742f, B5c = -3.290069515436081f, B6c = 2.324710524099774f;
    constexpr float E1 = -0.001780011052225777f, E2 = -0.0008164344596567469f, E3 = 0.007880878010261995f,
                    E4 = -0.1447110071732629f, E5 = 0.5823571654525552f, E6 = -0.45808210592918697f,
                    E7 = 0.015151515151515152f;

    // one wave per block; two independent trajectories (A,B) share it
    __shared__ alignas(16) float ybA[64], ybB[64];
    __shared__ alignas(16) float thA[HH], thB[HH];

    const int l  = threadIdx.x;
    const int d  = l & 31;    // dim owned (replicated across halves)
    const int hf = l >> 5;    // hidden-half owned in phase 2
    const int eA = blockIdx.x;
    const int eB = blockIdx.x + 256;

    // ---- shared weights resident in registers, K-paired (same layout as R3) ----
    f32x2 w1a2[16], w1b2[16], w2p[32];
#pragma unroll
    for (int i = 0; i < 16; ++i) {
        w1a2[i][0] = gW1[(2 * i) * HH + l];
        w1a2[i][1] = gW1[(2 * i + 1) * HH + l];
        w1b2[i][0] = gW1[(2 * i) * HH + l + 64];
        w1b2[i][1] = gW1[(2 * i + 1) * HH + l + 64];
    }
#pragma unroll
    for (int j = 0; j < 32; ++j) {
        const int h0 = hf * 64 + 2 * j;
        w2p[j][0] = gW2[h0 * DD + d];
        w2p[j][1] = gW2[(h0 + 1) * DD + d];
    }
    const float bh0 = gb1[l], bh1 = gb1[l + 64], b2d = gb2[d];

    auto ftanh = [](float v) -> float {
        float ex = fexp2(v * 2.885390081777927f);   // 2*log2(e)
        return 1.0f - frcpa(ex + 1.0f) * 2.0f;
    };

    // dual vector field: two independent chains interleaved to fill the latency shadow
    auto vfp = [&](float sAin, float sBin, float& oA, float& oB) {
        ybA[l] = sAin; ybB[l] = sBin;
        f32x2 hAa = {0,0}, hAb = {0,0}, hAc = {0,0}, hAd = {0,0};
        f32x2 hBa = {0,0}, hBb = {0,0}, hBc = {0,0}, hBd = {0,0};
        const f32x4* yA4 = (const f32x4*)ybA;
        const f32x4* yB4 = (const f32x4*)ybB;
#pragma unroll
        for (int i = 0; i < 8; ++i) {
            f32x4 vA = yA4[i], vB = yB4[i];
            f32x2 vAlo = {vA[0], vA[1]}, vAhi = {vA[2], vA[3]};
            f32x2 vBlo = {vB[0], vB[1]}, vBhi = {vB[2], vB[3]};
            pk_fma2(hAa, vAlo, w1a2[2 * i]);
            pk_fma2(hAb, vAhi, w1a2[2 * i + 1]);
            pk_fma2(hAc, vAlo, w1b2[2 * i]);
            pk_fma2(hAd, vAhi, w1b2[2 * i + 1]);
            pk_fma2(hBa, vBlo, w1a2[2 * i]);
            pk_fma2(hBb, vBhi, w1a2[2 * i + 1]);
            pk_fma2(hBc, vBlo, w1b2[2 * i]);
            pk_fma2(hBd, vBhi, w1b2[2 * i + 1]);
        }
        const float hA0 = bh0 + (hAa[0] + hAa[1]) + (hAb[0] + hAb[1]);
        const float hA1 = bh1 + (hAc[0] + hAc[1]) + (hAd[0] + hAd[1]);
        const float hB0 = bh0 + (hBa[0] + hBa[1]) + (hBb[0] + hBb[1]);
        const float hB1 = bh1 + (hBc[0] + hBc[1]) + (hBd[0] + hBd[1]);
        const float tA0 = ftanh(hA0), tA1 = ftanh(hA1);
        const float tB0 = ftanh(hB0), tB1 = ftanh(hB1);
        thA[l] = tA0; thA[l + 64] = tA1;
        thB[l] = tB0; thB[l + 64] = tB1;

        f32x2 aA0 = {0,0}, aA1 = {0,0}, aA2 = {0,0}, aA3 = {0,0};
        f32x2 aB0 = {0,0}, aB1 = {0,0}, aB2 = {0,0}, aB3 = {0,0};
        const f32x4* tA4 = (const f32x4*)(thA + (hf << 6));
        const f32x4* tB4 = (const f32x4*)(thB + (hf << 6));
#pragma unroll
        for (int i = 0; i < 4; ++i) {
            f32x4 vA0 = tA4[4 * i + 0], vA1 = tA4[4 * i + 1], vA2 = tA4[4 * i + 2], vA3 = tA4[4 * i + 3];
            f32x4 vB0 = tB4[4 * i + 0], vB1 = tB4[4 * i + 1], vB2 = tB4[4 * i + 2], vB3 = tB4[4 * i + 3];
            pk_fma2(aA0, f32x2{vA0[0], vA0[1]}, w2p[8 * i + 0]);
            pk_fma2(aA0, f32x2{vA0[2], vA0[3]}, w2p[8 * i + 1]);
            pk_fma2(aA1, f32x2{vA1[0], vA1[1]}, w2p[8 * i + 2]);
            pk_fma2(aA1, f32x2{vA1[2], vA1[3]}, w2p[8 * i + 3]);
            pk_fma2(aA2, f32x2{vA2[0], vA2[1]}, w2p[8 * i + 4]);
            pk_fma2(aA2, f32x2{vA2[2], vA2[3]}, w2p[8 * i + 5]);
            pk_fma2(aA3, f32x2{vA3[0], vA3[1]}, w2p[8 * i + 6]);
            pk_fma2(aA3, f32x2{vA3[2], vA3[3]}, w2p[8 * i + 7]);
            pk_fma2(aB0, f32x2{vB0[0], vB0[1]}, w2p[8 * i + 0]);
            pk_fma2(aB0, f32x2{vB0[2], vB0[3]}, w2p[8 * i + 1]);
            pk_fma2(aB1, f32x2{vB1[0], vB1[1]}, w2p[8 * i + 2]);
            pk_fma2(aB1, f32x2{vB1[2], vB1[3]}, w2p[8 * i + 3]);
            pk_fma2(aB2, f32x2{vB2[0], vB2[1]}, w2p[8 * i + 4]);
            pk_fma2(aB2, f32x2{vB2[2], vB2[3]}, w2p[8 * i + 5]);
            pk_fma2(aB3, f32x2{vB3[0], vB3[1]}, w2p[8 * i + 6]);
            pk_fma2(aB3, f32x2{vB3[2], vB3[3]}, w2p[8 * i + 7]);
        }
        f32x2 sA2 = (aA0 + aA1) + (aA2 + aA3);
        f32x2 sB2 = (aB0 + aB1) + (aB2 + aB3);
        const float sA = xadd32(sA2[0] + sA2[1]);
        const float sB = xadd32(sB2[0] + sB2[1]);
        oA = fmaf(-0.5f, sAin, sA + b2d);
        oB = fmaf(-0.5f, sBin, sB + b2d);
    };

    // ---- initial state ----
    float yA = gy0[eA * DD + d], yB = gy0[eB * DD + d];
    float tA = gts[0],          tB = gts[0];
    float dtA = 0.05f,          dtB = 0.05f;
    float k1A, k1B;
    vfp(yA, yB, k1A, k1B);

    gout[(hf ? eB : eA) * NTP * DD + d] = hf ? yB : yA;   // ti = 0

#pragma unroll 1
    for (int it = 1; it < NTP; ++it) {
        const float tb = gts[it];
#pragma unroll 1
        for (int s = 0; s < NINNER; ++s) {
            const bool doneA = (tA >= tb - 1e-9f);
            const bool doneB = (tB >= tb - 1e-9f);
            if (doneA && doneB) break;     // wave-uniform

            const float dtcA = fmaxf(fminf(dtA, tb - tA), 1e-12f);
            const float dtcB = fmaxf(fminf(dtB, tb - tB), 1e-12f);

            float sxA, sxB, stA, stB;
            float k2A, k2B, k3A, k3B, k4A, k4B, k5A, k5B, k6A, k6B, k7A, k7B;

            stA = fmaf(dtcA, A21 * k1A, yA);
            stB = fmaf(dtcB, A21 * k1B, yB);
            vfp(stA, stB, k2A, k2B);

            sxA = fmaf(A32, k2A, A31 * k1A);
            sxB = fmaf(A32, k2B, A31 * k1B);
            stA = fmaf(dtcA, sxA, yA); stB = fmaf(dtcB, sxB, yB);
            vfp(stA, stB, k3A, k3B);

            sxA = A41 * k1A; sxA = fmaf(A42, k2A, sxA); sxA = fmaf(A43, k3A, sxA);
            sxB = A41 * k1B; sxB = fmaf(A42, k2B, sxB); sxB = fmaf(A43, k3B, sxB);
            stA = fmaf(dtcA, sxA, yA); stB = fmaf(dtcB, sxB, yB);
            vfp(stA, stB, k4A, k4B);

            sxA = A51 * k1A; sxA = fmaf(A52, k2A, sxA); sxA = fmaf(A53, k3A, sxA); sxA = fmaf(A54, k4A, sxA);
            sxB = A51 * k1B; sxB = fmaf(A52, k2B, sxB); sxB = fmaf(A53, k3B, sxB); sxB = fmaf(A54, k4B, sxB);
            stA = fmaf(dtcA, sxA, yA); stB = fmaf(dtcB, sxB, yB);
            vfp(stA, stB, k5A, k5B);

            sxA = A61 * k1A; sxA = fmaf(A62, k2A, sxA); sxA = fmaf(A63, k3A, sxA); sxA = fmaf(A64, k4A, sxA); sxA = fmaf(A65, k5A, sxA);
            sxB = A61 * k1B; sxB = fmaf(A62, k2B, sxB); sxB = fmaf(A63, k3B, sxB); sxB = fmaf(A64, k4B, sxB); sxB = fmaf(A65, k5B, sxB);
            stA = fmaf(dtcA, sxA, yA); stB = fmaf(dtcB, sxB, yB);
            vfp(stA, stB, k6A, k6B);

            sxA = B1c * k1A; sxA = fmaf(B2c, k2A, sxA); sxA = fmaf(B3c, k3A, sxA);
            sxA = fmaf(B4c, k4A, sxA); sxA = fmaf(B5c, k5A, sxA); sxA = fmaf(B6c, k6A, sxA);
            sxB = B1c * k1B; sxB = fmaf(B2c, k2B, sxB); sxB = fmaf(B3c, k3B, sxB);
            sxB = fmaf(B4c, k4B, sxB); sxB = fmaf(B5c, k5B, sxB); sxB = fmaf(B6c, k6B, sxB);
            const float ynA = fmaf(dtcA, sxA, yA);
            const float ynB = fmaf(dtcB, sxB, yB);
            vfp(ynA, ynB, k7A, k7B);

            sxA = E1 * k1A; sxA = fmaf(E2, k2A, sxA); sxA = fmaf(E3, k3A, sxA); sxA = fmaf(E4, k4A, sxA);
            sxA = fmaf(E5, k5A, sxA); sxA = fmaf(E6, k6A, sxA); sxA = fmaf(E7, k7A, sxA);
            sxB = E1 * k1B; sxB = fmaf(E2, k2B, sxB); sxB = fmaf(E3, k3B, sxB); sxB = fmaf(E4, k4B, sxB);
            sxB = fmaf(E5, k5B, sxB); sxB = fmaf(E6, k6B, sxB); sxB = fmaf(E7, k7B, sxB);
            const float errA = dtcA * sxA;
            const float errB = dtcB * sxB;

            const float tolA = fmaf(0.001f, fmaxf(fabsf(yA), fabsf(ynA)), 1e-06f);
            const float tolB = fmaf(0.001f, fmaxf(fabsf(yB), fabsf(ynB)), 1e-06f);
            float qA = errA * frcpa(tolA); qA *= qA;
            float qB = errB * frcpa(tolB); qB *= qB;
            // both halves hold a full 32-dim replica -> 64-lane sum = 2x sum; scale 1/64
            const float enA2 = wave_sum(qA) * (1.0f / 64.0f);
            const float enB2 = wave_sum(qB) * (1.0f / 64.0f);

            const bool accA = (enA2 <= 1.0f) && !doneA;
            const bool accB = (enB2 <= 1.0f) && !doneB;

            float fA = 0.9f * fexp2(-0.1f * flog2(fmaxf(enA2, 1e-20f)));
            float fB = 0.9f * fexp2(-0.1f * flog2(fmaxf(enB2, 1e-20f)));
            fA = fminf(fmaxf(fA, 0.1f), 5.0f);
            fB = fminf(fmaxf(fB, 0.1f), 5.0f);

            dtA = doneA ? dtA : dtcA * fA;
            dtB = doneB ? dtB : dtcB * fB;
            tA  = accA ? (tA + dtcA) : tA;
            tB  = accB ? (tB + dtcB) : tB;
            yA  = accA ? ynA : yA;
            yB  = accB ? ynB : yB;
            k1A = accA ? k7A : k1A;
            k1B = accB ? k7B : k1B;
        }
        gout[(hf ? eB : eA) * NTP * DD + it * DD + d] = hf ? yB : yA;
    }
}

extern "C" void kernel_launch(void* const* d_in, const int* in_sizes, int n_in,
                              void* d_out, int out_size, void* d_ws, size_t ws_size,
                              hipStream_t stream) {
    (void)in_sizes; (void)n_in; (void)out_size; (void)d_ws; (void)ws_size;
    const float* y0 = (const float*)d_in[0];
    const float* ts = (const float*)d_in[1];
    const float* W1 = (const float*)d_in[2];
    const float* b1 = (const float*)d_in[3];
    const float* W2 = (const float*)d_in[4];
    const float* b2 = (const float*)d_in[5];
    ude_kernel<<<dim3(NB / 2), dim3(64), 0, stream>>>(y0, ts, W1, b1, W2, b2, (float*)d_out);
}

// Round 5
// 223.602 us; speedup vs baseline: 1.8339x; 1.8339x over previous
//
#include <hip/hip_runtime.h>

typedef float f32x2 __attribute__((ext_vector_type(2)));
typedef float f32x4 __attribute__((ext_vector_type(4)));

#define NB 512
#define DD 32
#define HH 128
#define NTP 64
#define NINNER 8

// packed dual-FP32 FMA: acc.lo += a.lo*b.lo ; acc.hi += a.hi*b.hi
__device__ __forceinline__ void pk_fma2(f32x2& acc, f32x2 a, f32x2 b) {
    asm("v_pk_fma_f32 %0, %1, %2, %0" : "+v"(acc) : "v"(a), "v"(b));
}
// hardware transcendentals (avoid glibc math.h macro collisions)
__device__ __forceinline__ float fexp2(float x) { float r; asm("v_exp_f32 %0, %1" : "=v"(r) : "v"(x)); return r; }
__device__ __forceinline__ float flog2(float x) { float r; asm("v_log_f32 %0, %1" : "=v"(r) : "v"(x)); return r; }
__device__ __forceinline__ float frcpa(float x) { float r; asm("v_rcp_f32 %0, %1" : "=v"(r) : "v"(x)); return r; }

__device__ __forceinline__ float rdlane(float x, int i) {
    return __int_as_float(__builtin_amdgcn_readlane(__float_as_int(x), i));
}

// x + value_from_lane(l^32) via VALU permlane (vs ds_bpermute ~50cyc)
__device__ __forceinline__ float xadd32(float x) {
#if __has_builtin(__builtin_amdgcn_permlane32_swap)
    auto r = __builtin_amdgcn_permlane32_swap(__float_as_int(x), __float_as_int(x), false, false);
    return __int_as_float(r[0]) + __int_as_float(r[1]);
#else
    return x + __shfl_xor(x, 32, 64);
#endif
}

#define DPP_ADD(s, ctrl) \
    s += __int_as_float(__builtin_amdgcn_update_dpp(0, __float_as_int(s), ctrl, 0xf, 0xf, true))

// 64-lane sum -> wave-uniform scalar (DPP ladder + readlane 63)
__device__ __forceinline__ float wave_sum(float s) {
    DPP_ADD(s, 0x111);  // row_shr:1
    DPP_ADD(s, 0x112);  // row_shr:2
    DPP_ADD(s, 0x114);  // row_shr:4
    DPP_ADD(s, 0x118);  // row_shr:8
    DPP_ADD(s, 0x142);  // row_bcast:15
    DPP_ADD(s, 0x143);  // row_bcast:31
    return rdlane(s, 63);
}

__global__ __launch_bounds__(128, 1)
void ude_kernel(const float* __restrict__ gy0, const float* __restrict__ gts,
                const float* __restrict__ gW1, const float* __restrict__ gb1,
                const float* __restrict__ gW2, const float* __restrict__ gb2,
                float* __restrict__ gout)
{
    constexpr float A21 = 0.161f;
    constexpr float A31 = -0.008480655492356989f, A32 = 0.335480655492357f;
    constexpr float A41 = 2.8971530571054935f, A42 = -6.359448489975075f, A43 = 4.3622954328695815f;
    constexpr float A51 = 5.325864828439257f, A52 = -11.748883564062828f, A53 = 7.4955393428898365f, A54 = -0.09249506636175525f;
    constexpr float A61 = 5.86145544294642f, A62 = -12.92096931784711f, A63 = 8.159367898576159f, A64 = -0.071584973281401f, A65 = -0.028269050394068383f;
    constexpr float B1c = 0.09646076681806523f, B2c = 0.01f, B3c = 0.4798896504144996f,
                    B4c = 1.379008574103742f, B5c = -3.290069515436081f, B6c = 2.324710524099774f;
    constexpr float E1 = -0.001780011052225777f, E2 = -0.0008164344596567469f, E3 = 0.007880878010261995f,
                    E4 = -0.1447110071732629f, E5 = 0.5823571654525552f, E6 = -0.45808210592918697f,
                    E7 = 0.015151515151515152f;

    // 2 independent waves per block (different elements); per-wave LDS, no barriers
    __shared__ alignas(16) float thb[2][HH];

    const int tid = threadIdx.x;
    const int wid = tid >> 6;
    const int l   = tid & 63;
    const int d   = l & 31;   // dim owned (lanes 32-63 hold replicas)
    const int hf  = l >> 5;   // hidden-half owned in phase 2
    const int e   = blockIdx.x * 2 + wid;   // one element per wave

    float* th = thb[wid];

    // ---- weights resident in registers ----
    float w1a[DD], w1b[DD];           // W1 columns l and l+64 (scalar: FMA with SGPR y)
#pragma unroll
    for (int i = 0; i < DD; ++i) {
        w1a[i] = gW1[i * HH + l];
        w1b[i] = gW1[i * HH + l + 64];
    }
    f32x2 w2p[32];                    // W2 half-column for output dim d, K-paired
#pragma unroll
    for (int j = 0; j < 32; ++j) {
        const int h0 = hf * 64 + 2 * j;
        w2p[j][0] = gW2[h0 * DD + d];
        w2p[j][1] = gW2[(h0 + 1) * DD + d];
    }
    const float bh0 = gb1[l], bh1 = gb1[l + 64], b2d = gb2[d];

    auto ftanh = [](float v) -> float {
        float ex = fexp2(v * 2.885390081777927f);   // 2*log2(e)
        return 1.0f - frcpa(ex + 1.0f) * 2.0f;
    };

    // vector field; input st distributed (lane d owns dim d)
    auto vf = [&](float st) -> float {
        // broadcast state to SGPRs (no LDS round trip)
        float s[DD];
#pragma unroll
        for (int i = 0; i < DD; ++i) s[i] = rdlane(st, i);

        // phase 1: h[l], h[l+64]; 4 independent chains each
        float a0 = 0.f, a1 = 0.f, a2 = 0.f, a3 = 0.f;
        float c0 = 0.f, c1 = 0.f, c2 = 0.f, c3 = 0.f;
#pragma unroll
        for (int i = 0; i < 8; ++i) {
            a0 = fmaf(s[4 * i + 0], w1a[4 * i + 0], a0);
            a1 = fmaf(s[4 * i + 1], w1a[4 * i + 1], a1);
            a2 = fmaf(s[4 * i + 2], w1a[4 * i + 2], a2);
            a3 = fmaf(s[4 * i + 3], w1a[4 * i + 3], a3);
            c0 = fmaf(s[4 * i + 0], w1b[4 * i + 0], c0);
            c1 = fmaf(s[4 * i + 1], w1b[4 * i + 1], c1);
            c2 = fmaf(s[4 * i + 2], w1b[4 * i + 2], c2);
            c3 = fmaf(s[4 * i + 3], w1b[4 * i + 3], c3);
        }
        const float h0 = bh0 + ((a0 + a1) + (a2 + a3));
        const float h1 = bh1 + ((c0 + c1) + (c2 + c3));
        const float t0 = ftanh(h0);
        const float t1 = ftanh(h1);
        th[l] = t0;
        th[l + 64] = t1;

        // phase 2: transpose via LDS broadcast reads + packed FMA
        f32x2 p0 = {0.f, 0.f}, p1 = {0.f, 0.f}, p2 = {0.f, 0.f}, p3 = {0.f, 0.f};
        const f32x4* t4 = (const f32x4*)(th + (hf << 6));
#pragma unroll
        for (int i = 0; i < 4; ++i) {
            f32x4 va = t4[4 * i + 0], vb = t4[4 * i + 1], vc = t4[4 * i + 2], vd = t4[4 * i + 3];
            pk_fma2(p0, f32x2{va[0], va[1]}, w2p[8 * i + 0]);
            pk_fma2(p0, f32x2{va[2], va[3]}, w2p[8 * i + 1]);
            pk_fma2(p1, f32x2{vb[0], vb[1]}, w2p[8 * i + 2]);
            pk_fma2(p1, f32x2{vb[2], vb[3]}, w2p[8 * i + 3]);
            pk_fma2(p2, f32x2{vc[0], vc[1]}, w2p[8 * i + 4]);
            pk_fma2(p2, f32x2{vc[2], vc[3]}, w2p[8 * i + 5]);
            pk_fma2(p3, f32x2{vd[0], vd[1]}, w2p[8 * i + 6]);
            pk_fma2(p3, f32x2{vd[2], vd[3]}, w2p[8 * i + 7]);
        }
        f32x2 ps = (p0 + p1) + (p2 + p3);
        const float ssum = xadd32(ps[0] + ps[1]);   // combine hidden halves (VALU)
        return fmaf(-0.5f, st, ssum + b2d);
    };

    // ---- initial state ----
    float y  = gy0[e * DD + d];
    float t  = gts[0];
    float dt = 0.05f;
    float k1 = vf(y);

    if (l < 32) gout[e * NTP * DD + l] = y;       // ti = 0

#pragma unroll 1
    for (int it = 1; it < NTP; ++it) {
        const float tb = gts[it];
#pragma unroll 1
        for (int s = 0; s < NINNER; ++s) {
            if (t >= tb - 1e-9f) break;           // wave-uniform: rest are provable no-ops

            const float dtc = fmaxf(fminf(dt, tb - t), 1e-12f);

            float st, sx;
            st = fmaf(dtc, A21 * k1, y);
            const float k2 = vf(st);

            sx = fmaf(A32, k2, A31 * k1);
            st = fmaf(dtc, sx, y);
            const float k3 = vf(st);

            sx = A41 * k1; sx = fmaf(A42, k2, sx); sx = fmaf(A43, k3, sx);
            st = fmaf(dtc, sx, y);
            const float k4 = vf(st);

            sx = A51 * k1; sx = fmaf(A52, k2, sx); sx = fmaf(A53, k3, sx); sx = fmaf(A54, k4, sx);
            st = fmaf(dtc, sx, y);
            const float k5 = vf(st);

            sx = A61 * k1; sx = fmaf(A62, k2, sx); sx = fmaf(A63, k3, sx); sx = fmaf(A64, k4, sx); sx = fmaf(A65, k5, sx);
            st = fmaf(dtc, sx, y);
            const float k6 = vf(st);

            sx = B1c * k1; sx = fmaf(B2c, k2, sx); sx = fmaf(B3c, k3, sx);
            sx = fmaf(B4c, k4, sx); sx = fmaf(B5c, k5, sx); sx = fmaf(B6c, k6, sx);
            const float ynew = fmaf(dtc, sx, y);
            const float k7 = vf(ynew);

            sx = E1 * k1; sx = fmaf(E2, k2, sx); sx = fmaf(E3, k3, sx); sx = fmaf(E4, k4, sx);
            sx = fmaf(E5, k5, sx); sx = fmaf(E6, k6, sx); sx = fmaf(E7, k7, sx);
            const float err = dtc * sx;

            const float tol = fmaf(0.001f, fmaxf(fabsf(y), fabsf(ynew)), 1e-06f);
            float q = err * frcpa(tol);
            q *= q;
            // both halves hold a full replica -> 64-lane sum = 2x; scale 1/64
            const float en2 = wave_sum(q) * (1.0f / 64.0f);

            const bool acc = (en2 <= 1.0f);
            float fac = 0.9f * fexp2(-0.1f * flog2(fmaxf(en2, 1e-20f)));
            fac = fminf(fmaxf(fac, 0.1f), 5.0f);

            dt = dtc * fac;
            t  = acc ? (t + dtc) : t;
            y  = acc ? ynew : y;
            k1 = acc ? k7 : k1;
        }
        if (l < 32) gout[e * NTP * DD + it * DD + l] = y;
    }
}

extern "C" void kernel_launch(void* const* d_in, const int* in_sizes, int n_in,
                              void* d_out, int out_size, void* d_ws, size_t ws_size,
                              hipStream_t stream) {
    (void)in_sizes; (void)n_in; (void)out_size; (void)d_ws; (void)ws_size;
    const float* y0 = (const float*)d_in[0];
    const float* ts = (const float*)d_in[1];
    const float* W1 = (const float*)d_in[2];
    const float* b1 = (const float*)d_in[3];
    const float* W2 = (const float*)d_in[4];
    const float* b2 = (const float*)d_in[5];
    ude_kernel<<<dim3(NB / 2), dim3(128), 0, stream>>>(y0, ts, W1, b1, W2, b2, (float*)d_out);
}

// Round 6
// 208.782 us; speedup vs baseline: 1.9641x; 1.0710x over previous
//
#include <hip/hip_runtime.h>

typedef float f32x2 __attribute__((ext_vector_type(2)));
typedef float f32x4 __attribute__((ext_vector_type(4)));

#define NB 512
#define DD 32
#define HH 128
#define NTP 64
#define NINNER 8

// packed dual-FP32 FMA: acc.lo += a.lo*b.lo ; acc.hi += a.hi*b.hi
__device__ __forceinline__ void pk_fma2(f32x2& acc, f32x2 a, f32x2 b) {
    asm("v_pk_fma_f32 %0, %1, %2, %0" : "+v"(acc) : "v"(a), "v"(b));
}
// same, but the multiplicand pair lives in an SGPR pair (wave-uniform broadcast)
__device__ __forceinline__ void pk_fma_s(f32x2& acc, f32x2 s, f32x2 w) {
    asm("v_pk_fma_f32 %0, %1, %2, %0" : "+v"(acc) : "s"(s), "v"(w));
}
// hardware transcendentals (avoid glibc math.h macro collisions)
__device__ __forceinline__ float fexp2(float x) { float r; asm("v_exp_f32 %0, %1" : "=v"(r) : "v"(x)); return r; }
__device__ __forceinline__ float flog2(float x) { float r; asm("v_log_f32 %0, %1" : "=v"(r) : "v"(x)); return r; }
__device__ __forceinline__ float frcpa(float x) { float r; asm("v_rcp_f32 %0, %1" : "=v"(r) : "v"(x)); return r; }

__device__ __forceinline__ float rdlane(float x, int i) {
    return __int_as_float(__builtin_amdgcn_readlane(__float_as_int(x), i));
}

// x + value_from_lane(l^32) via VALU permlane (vs ds_bpermute ~50cyc)
__device__ __forceinline__ float xadd32(float x) {
#if __has_builtin(__builtin_amdgcn_permlane32_swap)
    auto r = __builtin_amdgcn_permlane32_swap(__float_as_int(x), __float_as_int(x), false, false);
    return __int_as_float(r[0]) + __int_as_float(r[1]);
#else
    return x + __shfl_xor(x, 32, 64);
#endif
}

#define DPP_ADD(s, ctrl) \
    s += __int_as_float(__builtin_amdgcn_update_dpp(0, __float_as_int(s), ctrl, 0xf, 0xf, true))

// 64-lane sum -> wave-uniform scalar (DPP ladder + readlane 63)
__device__ __forceinline__ float wave_sum(float s) {
    DPP_ADD(s, 0x111);  // row_shr:1
    DPP_ADD(s, 0x112);  // row_shr:2
    DPP_ADD(s, 0x114);  // row_shr:4
    DPP_ADD(s, 0x118);  // row_shr:8
    DPP_ADD(s, 0x142);  // row_bcast:15
    DPP_ADD(s, 0x143);  // row_bcast:31
    return rdlane(s, 63);
}

__global__ __launch_bounds__(128, 1)
void ude_kernel(const float* __restrict__ gy0, const float* __restrict__ gts,
                const float* __restrict__ gW1, const float* __restrict__ gb1,
                const float* __restrict__ gW2, const float* __restrict__ gb2,
                float* __restrict__ gout)
{
    constexpr float A21 = 0.161f;
    constexpr float A31 = -0.008480655492356989f, A32 = 0.335480655492357f;
    constexpr float A41 = 2.8971530571054935f, A42 = -6.359448489975075f, A43 = 4.3622954328695815f;
    constexpr float A51 = 5.325864828439257f, A52 = -11.748883564062828f, A53 = 7.4955393428898365f, A54 = -0.09249506636175525f;
    constexpr float A61 = 5.86145544294642f, A62 = -12.92096931784711f, A63 = 8.159367898576159f, A64 = -0.071584973281401f, A65 = -0.028269050394068383f;
    constexpr float B1c = 0.09646076681806523f, B2c = 0.01f, B3c = 0.4798896504144996f,
                    B4c = 1.379008574103742f, B5c = -3.290069515436081f, B6c = 2.324710524099774f;
    constexpr float E1 = -0.001780011052225777f, E2 = -0.0008164344596567469f, E3 = 0.007880878010261995f,
                    E4 = -0.1447110071732629f, E5 = 0.5823571654525552f, E6 = -0.45808210592918697f,
                    E7 = 0.015151515151515152f;

    // 2 independent waves per block (different elements); per-wave LDS, no barriers
    __shared__ alignas(16) float thb[2][HH];

    const int tid = threadIdx.x;
    const int wid = tid >> 6;
    const int l   = tid & 63;
    const int d   = l & 31;   // dim owned (lanes 32-63 hold replicas)
    const int hf  = l >> 5;   // hidden-half owned in phase 2
    const int e   = blockIdx.x * 2 + wid;   // one element per wave

    float* th = thb[wid];

    // ---- weights resident in registers, K-paired for packed FMA ----
    f32x2 w1a2[16], w1b2[16];         // W1 columns l and l+64, paired over K
#pragma unroll
    for (int i = 0; i < 16; ++i) {
        w1a2[i][0] = gW1[(2 * i) * HH + l];
        w1a2[i][1] = gW1[(2 * i + 1) * HH + l];
        w1b2[i][0] = gW1[(2 * i) * HH + l + 64];
        w1b2[i][1] = gW1[(2 * i + 1) * HH + l + 64];
    }
    f32x2 w2p[32];                    // W2 half-column for output dim d, K-paired
#pragma unroll
    for (int j = 0; j < 32; ++j) {
        const int h0 = hf * 64 + 2 * j;
        w2p[j][0] = gW2[h0 * DD + d];
        w2p[j][1] = gW2[(h0 + 1) * DD + d];
    }
    const float bh0 = gb1[l], bh1 = gb1[l + 64], b2d = gb2[d];

    auto ftanh = [](float v) -> float {
        float ex = fexp2(v * 2.885390081777927f);   // 2*log2(e)
        return 1.0f - frcpa(ex + 1.0f) * 2.0f;
    };

    // vector field; input st distributed (lane d owns dim d)
    auto vf = [&](float st) -> float {
        // broadcast state into 16 wave-uniform SGPR pairs (no LDS round trip)
        f32x2 sp[16];
#pragma unroll
        for (int i = 0; i < 16; ++i) {
            sp[i][0] = rdlane(st, 2 * i);
            sp[i][1] = rdlane(st, 2 * i + 1);
        }

        // phase 1: h[l], h[l+64] via packed FMA, SGPR-pair x VGPR-pair
        f32x2 ha0 = {0.f, 0.f}, ha1 = {0.f, 0.f};
        f32x2 hb0 = {0.f, 0.f}, hb1 = {0.f, 0.f};
#pragma unroll
        for (int i = 0; i < 8; ++i) {
            pk_fma_s(ha0, sp[2 * i],     w1a2[2 * i]);
            pk_fma_s(ha1, sp[2 * i + 1], w1a2[2 * i + 1]);
            pk_fma_s(hb0, sp[2 * i],     w1b2[2 * i]);
            pk_fma_s(hb1, sp[2 * i + 1], w1b2[2 * i + 1]);
        }
        const float h0 = bh0 + ((ha0[0] + ha0[1]) + (ha1[0] + ha1[1]));
        const float h1 = bh1 + ((hb0[0] + hb0[1]) + (hb1[0] + hb1[1]));
        const float t0 = ftanh(h0);
        const float t1 = ftanh(h1);
        th[l] = t0;
        th[l + 64] = t1;

        // phase 2: transpose via LDS broadcast reads + packed FMA
        f32x2 p0 = {0.f, 0.f}, p1 = {0.f, 0.f}, p2 = {0.f, 0.f}, p3 = {0.f, 0.f};
        const f32x4* t4 = (const f32x4*)(th + (hf << 6));
#pragma unroll
        for (int i = 0; i < 4; ++i) {
            f32x4 va = t4[4 * i + 0], vb = t4[4 * i + 1], vc = t4[4 * i + 2], vd = t4[4 * i + 3];
            pk_fma2(p0, f32x2{va[0], va[1]}, w2p[8 * i + 0]);
            pk_fma2(p0, f32x2{va[2], va[3]}, w2p[8 * i + 1]);
            pk_fma2(p1, f32x2{vb[0], vb[1]}, w2p[8 * i + 2]);
            pk_fma2(p1, f32x2{vb[2], vb[3]}, w2p[8 * i + 3]);
            pk_fma2(p2, f32x2{vc[0], vc[1]}, w2p[8 * i + 4]);
            pk_fma2(p2, f32x2{vc[2], vc[3]}, w2p[8 * i + 5]);
            pk_fma2(p3, f32x2{vd[0], vd[1]}, w2p[8 * i + 6]);
            pk_fma2(p3, f32x2{vd[2], vd[3]}, w2p[8 * i + 7]);
        }
        f32x2 ps = (p0 + p1) + (p2 + p3);
        const float ssum = xadd32(ps[0] + ps[1]);   // combine hidden halves (VALU)
        return fmaf(-0.5f, st, ssum + b2d);
    };

    // ---- initial state ----
    float y  = gy0[e * DD + d];
    float t  = gts[0];
    float dt = 0.05f;
    float k1 = vf(y);

    if (l < 32) gout[e * NTP * DD + l] = y;       // ti = 0

#pragma unroll 1
    for (int it = 1; it < NTP; ++it) {
        const float tb = gts[it];
#pragma unroll 1
        for (int s = 0; s < NINNER; ++s) {
            if (t >= tb - 1e-9f) break;           // wave-uniform: rest are provable no-ops

            const float dtc = fmaxf(fminf(dt, tb - t), 1e-12f);

            float st, sx;
            st = fmaf(dtc, A21 * k1, y);
            const float k2 = vf(st);

            sx = fmaf(A32, k2, A31 * k1);
            st = fmaf(dtc, sx, y);
            const float k3 = vf(st);

            sx = A41 * k1; sx = fmaf(A42, k2, sx); sx = fmaf(A43, k3, sx);
            st = fmaf(dtc, sx, y);
            const float k4 = vf(st);

            sx = A51 * k1; sx = fmaf(A52, k2, sx); sx = fmaf(A53, k3, sx); sx = fmaf(A54, k4, sx);
            st = fmaf(dtc, sx, y);
            const float k5 = vf(st);

            sx = A61 * k1; sx = fmaf(A62, k2, sx); sx = fmaf(A63, k3, sx); sx = fmaf(A64, k4, sx); sx = fmaf(A65, k5, sx);
            st = fmaf(dtc, sx, y);
            const float k6 = vf(st);

            sx = B1c * k1; sx = fmaf(B2c, k2, sx); sx = fmaf(B3c, k3, sx);
            sx = fmaf(B4c, k4, sx); sx = fmaf(B5c, k5, sx); sx = fmaf(B6c, k6, sx);
            const float ynew = fmaf(dtc, sx, y);
            const float k7 = vf(ynew);

            sx = E1 * k1; sx = fmaf(E2, k2, sx); sx = fmaf(E3, k3, sx); sx = fmaf(E4, k4, sx);
            sx = fmaf(E5, k5, sx); sx = fmaf(E6, k6, sx); sx = fmaf(E7, k7, sx);
            const float err = dtc * sx;

            const float tol = fmaf(0.001f, fmaxf(fabsf(y), fabsf(ynew)), 1e-06f);
            float q = err * frcpa(tol);
            q *= q;
            // both halves hold a full replica -> 64-lane sum = 2x; scale 1/64
            const float en2 = wave_sum(q) * (1.0f / 64.0f);

            const bool acc = (en2 <= 1.0f);
            float fac = 0.9f * fexp2(-0.1f * flog2(fmaxf(en2, 1e-20f)));
            fac = fminf(fmaxf(fac, 0.1f), 5.0f);

            dt = dtc * fac;
            t  = acc ? (t + dtc) : t;
            y  = acc ? ynew : y;
            k1 = acc ? k7 : k1;
        }
        if (l < 32) gout[e * NTP * DD + it * DD + l] = y;
    }
}

extern "C" void kernel_launch(void* const* d_in, const int* in_sizes, int n_in,
                              void* d_out, int out_size, void* d_ws, size_t ws_size,
                              hipStream_t stream) {
    (void)in_sizes; (void)n_in; (void)out_size; (void)d_ws; (void)ws_size;
    const float* y0 = (const float*)d_in[0];
    const float* ts = (const float*)d_in[1];
    const float* W1 = (const float*)d_in[2];
    const float* b1 = (const float*)d_in[3];
    const float* W2 = (const float*)d_in[4];
    const float* b2 = (const float*)d_in[5];
    ude_kernel<<<dim3(NB / 2), dim3(128), 0, stream>>>(y0, ts, W1, b1, W2, b2, (float*)d_out);
}